// Round 9
// baseline (375.927 us; speedup 1.0000x reference)
//
#include <hip/hip_runtime.h>
#include <hip/hip_bf16.h>

#define N_NODES_C 100000
#define N_EDGES_C 150000
#define DC 512
#define NG 64

typedef float f32x4 __attribute__((ext_vector_type(4)));
typedef short s16x8 __attribute__((ext_vector_type(8)));
typedef unsigned int u32;

__device__ __forceinline__ short f2bf(float f) {
    union { float f; unsigned u; } c; c.f = f;
    unsigned r = c.u + 0x7fffu + ((c.u >> 16) & 1u);
    return (short)(r >> 16);
}
__device__ __forceinline__ float bf2f(short v) {
    union { unsigned u; float f; } c;
    c.u = ((unsigned)(unsigned short)v) << 16;
    return c.f;
}

// async global->LDS, 16B per lane; LDS dest is wave-uniform base + lane*16
__device__ __forceinline__ void gload16(const void* g, void* l) {
    __builtin_amdgcn_global_load_lds((const __attribute__((address_space(1))) u32*)g,
                                     (__attribute__((address_space(3))) u32*)l,
                                     16, 0, 0);
}

// ---------------- small kernels ----------------

__global__ void zero_k(float* s, float* aggs, int* cnt, float* gsum, float* gcnt) {
    int i = blockIdx.x * 256 + threadIdx.x;
    if (i < N_NODES_C) { s[i] = 0.f; aggs[i] = 0.f; cnt[i] = 0; }
    if (i < NG) { gsum[i] = 0.f; gcnt[i] = 0.f; }
}

// out[n][k] = bf16(in[k][n]); in is [512][512] f32 row-major
__global__ void transpose_w(const float* __restrict__ in, short* __restrict__ out) {
    __shared__ float tile[32][33];
    int tx = threadIdx.x & 31;
    int ty = threadIdx.x >> 5;  // 0..7
    int k0 = blockIdx.y * 32;
    int n0 = blockIdx.x * 32;
#pragma unroll
    for (int i = 0; i < 4; ++i)
        tile[ty + i * 8][tx] = in[(size_t)(k0 + ty + i * 8) * DC + n0 + tx];
    __syncthreads();
#pragma unroll
    for (int i = 0; i < 4; ++i)
        out[(size_t)(n0 + ty + i * 8) * DC + k0 + tx] = f2bf(tile[tx][ty + i * 8]);
}

// ---------------- counting sort of edges by dst ----------------

__global__ void hist_k(const int* __restrict__ ei, int* __restrict__ cnt) {
    int e = blockIdx.x * 256 + threadIdx.x;
    if (e < N_EDGES_C) atomicAdd(&cnt[ei[N_EDGES_C + e]], 1);
}

__global__ void scan1_k(const int* __restrict__ cnt, int* __restrict__ off,
                        int* __restrict__ bsum) {
    __shared__ int sh[1024];
    int tid = threadIdx.x;
    int i = blockIdx.x * 1024 + tid;
    int v = (i < N_NODES_C) ? cnt[i] : 0;
    sh[tid] = v;
    __syncthreads();
    for (int d = 1; d < 1024; d <<= 1) {
        int t = (tid >= d) ? sh[tid - d] : 0;
        __syncthreads();
        sh[tid] += t;
        __syncthreads();
    }
    if (i < N_NODES_C) off[i] = sh[tid] - v;  // exclusive
    if (tid == 1023) bsum[blockIdx.x] = sh[1023];
}

#define NSCAN_BLK 98  // ceil(100000/1024)

__global__ void scan2_k(int* __restrict__ bsum) {
    __shared__ int sh[128];
    int tid = threadIdx.x;
    int v = (tid < NSCAN_BLK) ? bsum[tid] : 0;
    sh[tid] = v;
    __syncthreads();
    for (int d = 1; d < 128; d <<= 1) {
        int t = (tid >= d) ? sh[tid - d] : 0;
        __syncthreads();
        sh[tid] += t;
        __syncthreads();
    }
    if (tid < NSCAN_BLK) bsum[tid] = sh[tid] - v;  // exclusive
}

__global__ void scan3_k(int* __restrict__ off, const int* __restrict__ bsum) {
    int i = blockIdx.x * 1024 + threadIdx.x;
    if (i < N_NODES_C) off[i] += bsum[blockIdx.x];
}

// place: off becomes end-cursor; after completion off[i] = start of node i+1
__global__ void place_k(const int* __restrict__ ei, int* __restrict__ off,
                        int* __restrict__ ssrc) {
    int e = blockIdx.x * 256 + threadIdx.x;
    if (e < N_EDGES_C) {
        int d = ei[N_EDGES_C + e];
        int p = atomicAdd(&off[d], 1);
        ssrc[p] = ei[e];
    }
}

// z1[i] = bf16(relu(y[i] + sum_{e:dst=i} y[src_e] + b1a)); 4 nodes/block, 64 lanes/node
__global__ void gather_relu_k(const short* __restrict__ y, const int* __restrict__ off,
                              const int* __restrict__ ssrc, const float* __restrict__ b1a,
                              short* __restrict__ z1) {
    int node = blockIdx.x * 4 + (threadIdx.x >> 6);
    if (node >= N_NODES_C) return;
    int t = threadIdx.x & 63;
    const int col = t * 8;
    int beg = (node == 0) ? 0 : off[node - 1];
    int end = off[node];
    s16x8 own = *(const s16x8*)(y + (size_t)node * DC + col);
    float acc[8];
#pragma unroll
    for (int q = 0; q < 8; ++q) acc[q] = bf2f(own[q]);
    int j = beg;
    for (; j + 2 <= end; j += 2) {
        int s0 = ssrc[j];
        int s1 = ssrc[j + 1];
        s16x8 r0 = *(const s16x8*)(y + (size_t)s0 * DC + col);
        s16x8 r1 = *(const s16x8*)(y + (size_t)s1 * DC + col);
#pragma unroll
        for (int q = 0; q < 8; ++q) acc[q] += bf2f(r0[q]) + bf2f(r1[q]);
    }
    if (j < end) {
        int s0 = ssrc[j];
        s16x8 r0 = *(const s16x8*)(y + (size_t)s0 * DC + col);
#pragma unroll
        for (int q = 0; q < 8; ++q) acc[q] += bf2f(r0[q]);
    }
    f32x4 bv0 = *(const f32x4*)(b1a + col);
    f32x4 bv1 = *(const f32x4*)(b1a + col + 4);
    s16x8 o;
    o[0] = f2bf(fmaxf(acc[0] + bv0.x, 0.f));
    o[1] = f2bf(fmaxf(acc[1] + bv0.y, 0.f));
    o[2] = f2bf(fmaxf(acc[2] + bv0.z, 0.f));
    o[3] = f2bf(fmaxf(acc[3] + bv0.w, 0.f));
    o[4] = f2bf(fmaxf(acc[4] + bv1.x, 0.f));
    o[5] = f2bf(fmaxf(acc[5] + bv1.y, 0.f));
    o[6] = f2bf(fmaxf(acc[6] + bv1.z, 0.f));
    o[7] = f2bf(fmaxf(acc[7] + bv1.w, 0.f));
    *(s16x8*)(z1 + (size_t)node * DC + col) = o;
}

// ---------------- scalar tail ----------------

__global__ void edge_scalar(const int* __restrict__ ei, const float* __restrict__ s,
                            float* __restrict__ aggs) {
    int e = blockIdx.x * 256 + threadIdx.x;
    if (e < N_EDGES_C) atomicAdd(&aggs[ei[N_EDGES_C + e]], s[ei[e]]);
}

__global__ void node_pool(const float* __restrict__ s, const float* __restrict__ aggs,
                          const int* __restrict__ batch, const float* __restrict__ b2a,
                          float* __restrict__ gsum, float* __restrict__ gcnt) {
    __shared__ float ls[NG], lc[NG];
    int t = threadIdx.x;
    if (t < NG) { ls[t] = 0.f; lc[t] = 0.f; }
    __syncthreads();
    int i = blockIdx.x * 256 + t;
    if (i < N_NODES_C) {
        float z2 = fmaxf(aggs[i] + s[i] + b2a[0], 0.0f);
        int g = batch[i];
        atomicAdd(&ls[g], z2);
        atomicAdd(&lc[g], 1.0f);
    }
    __syncthreads();
    if (t < NG && lc[t] != 0.f) {
        atomicAdd(&gsum[t], ls[t]);
        atomicAdd(&gcnt[t], lc[t]);
    }
}

__global__ void finalize_k(const float* gsum, const float* gcnt, const float* w2b,
                           const float* b2b, float* out) {
    int g = threadIdx.x;
    if (g < NG) {
        float c = fmaxf(gcnt[g], 1.0f);
        out[g] = gsum[g] / c * w2b[0] + b2b[0];
    }
}

// ---------------- deep-pipelined GEMM ----------------
// 256x128 tile, BK=64, 8 waves, TRIPLE-buffered LDS (3 x 48KB), depth-2
// prefetch with counted vmcnt(6), ONE barrier per K-tile. XOR chunk-swizzle
// (chunk ^= row&7) applied source-side for gload_lds and on frag ds_reads.
// ASRC 0: A f32, reg-staged + fused f32->bf16 (issue-early/write-late).
// ASRC 1: A bf16 via global_load_lds.
// EPI 1: h = relu(A@W + bias); s_out[row] += h . w2a
// EPI 2: C = A@W -> bf16
#define NKT8 8            // K tiles: 512/64
#define BUF_SHORTS 24576  // A 256*64 + B 128*64
#define LDS_BYTES (3 * BUF_SHORTS * 2)  // 147456
#define NWG8 1568         // 392 row tiles * 4 col tiles = 8 * 196
#define WPX8 196

#define VMCNT(n) asm volatile("s_waitcnt vmcnt(" #n ")")
#define LGKM0() asm volatile("s_waitcnt lgkmcnt(0)")
#define SCHEDB() __builtin_amdgcn_sched_barrier(0)
#define HWBAR() __builtin_amdgcn_s_barrier()

template <int ASRC, int EPI>
__global__ __launch_bounds__(512) void gemm8_k(const void* __restrict__ Ap,
                                               const short* __restrict__ Bt,
                                               const float* __restrict__ bias,
                                               short* __restrict__ Cout,
                                               const float* __restrict__ w2a,
                                               float* __restrict__ s_out) {
    extern __shared__ short lds[];

    const int tid = threadIdx.x;
    const int bid = blockIdx.x;
    const int lin = (bid & 7) * WPX8 + (bid >> 3);
    const int brow = (lin >> 2) * 256;
    const int bcol = (lin & 3) * 128;

    const int w    = tid >> 6;
    const int lane = tid & 63;
    const int wm   = w >> 1;    // 0..3 (row quadrant)
    const int wn   = w & 1;     // 0..1 (col half)
    const int lr   = lane & 15;
    const int lg   = lane >> 4; // 0..3 chunk group
    const int l3   = lane >> 3; // 0..7
    const int sc   = ((lane & 7) ^ l3) * 8;  // swizzled source chunk (shorts)

    f32x4 acc[4][4] = {};

    // ---- staging addresses ----
    const short* bsrc0 = Bt + (size_t)(bcol + 0 * 64 + w * 8 + l3) * DC + sc;
    const short* bsrc1 = Bt + (size_t)(bcol + 1 * 64 + w * 8 + l3) * DC + sc;
    const int boff0 = 16384 + (0 * 64 + w * 8) * 64;
    const int boff1 = 16384 + (1 * 64 + w * 8) * 64;

    const short* asrc[4];
    int aoff[4];
    const float* axsrc = nullptr;
    int awoff[4];
    if constexpr (ASRC == 1) {
#pragma unroll
        for (int i = 0; i < 4; ++i) {
            int r = brow + i * 64 + w * 8 + l3;
            if (r >= N_NODES_C) r = N_NODES_C - 1;  // clamp; stores guarded
            asrc[i] = (const short*)Ap + (size_t)r * DC + sc;
            aoff[i] = (i * 64 + w * 8) * 64;
        }
    } else {
        const int rAl = tid >> 1;  // 0..255: LDS row this thread stages
        int r = brow + rAl;
        if (r >= N_NODES_C) r = N_NODES_C - 1;
        axsrc = (const float*)Ap + (size_t)r * DC + (tid & 1) * 32;
#pragma unroll
        for (int j = 0; j < 4; ++j)
            awoff[j] = rAl * 64 + ((((tid & 1) * 4 + j) ^ (rAl & 7)) * 8);
    }

#define STAGE_B(t, sb_)                                  \
    do {                                                 \
        short* _p = &lds[(sb_)*BUF_SHORTS];              \
        gload16(bsrc0 + (t)*64, _p + boff0);             \
        gload16(bsrc1 + (t)*64, _p + boff1);             \
    } while (0)
#define STAGE_A1(t, sb_)                                 \
    do {                                                 \
        short* _p = &lds[(sb_)*BUF_SHORTS];              \
        gload16(asrc[0] + (t)*64, _p + aoff[0]);         \
        gload16(asrc[1] + (t)*64, _p + aoff[1]);         \
        gload16(asrc[2] + (t)*64, _p + aoff[2]);         \
        gload16(asrc[3] + (t)*64, _p + aoff[3]);         \
    } while (0)
#define LOAD_A0(t, fr)                                                    \
    _Pragma("unroll") for (int q = 0; q < 8; ++q)                         \
        fr[q] = *(const f32x4*)(axsrc + (t)*64 + q * 4);
#define WRITE_A0(sb_, fr)                                                 \
    do {                                                                  \
        short* _p = &lds[(sb_)*BUF_SHORTS];                               \
        _Pragma("unroll") for (int j = 0; j < 4; ++j) {                   \
            s16x8 _c;                                                     \
            _c[0] = f2bf(fr[2 * j].x);     _c[1] = f2bf(fr[2 * j].y);     \
            _c[2] = f2bf(fr[2 * j].z);     _c[3] = f2bf(fr[2 * j].w);     \
            _c[4] = f2bf(fr[2 * j + 1].x); _c[5] = f2bf(fr[2 * j + 1].y); \
            _c[6] = f2bf(fr[2 * j + 1].z); _c[7] = f2bf(fr[2 * j + 1].w); \
            *(s16x8*)&_p[awoff[j]] = _c;                                  \
        }                                                                 \
    } while (0)

    // ---- prologue: tiles 0 and 1 ----
    if constexpr (ASRC == 1) {
        STAGE_A1(0, 0); STAGE_B(0, 0);
        STAGE_A1(1, 1); STAGE_B(1, 1);
        VMCNT(6);  // tile 0 landed; tile 1's 6 still in flight
        SCHEDB();
        HWBAR();
    } else {
        f32x4 p0[8], p1[8];
        LOAD_A0(0, p0);
        STAGE_B(0, 0);
        LOAD_A0(1, p1);
        STAGE_B(1, 1);
        WRITE_A0(0, p0);  // compiler inserts precise vmcnt for p0 use
        WRITE_A0(1, p1);
        VMCNT(0);         // prologue drain: B0,B1 landed
        LGKM0();          // ds_writes visible
        SCHEDB();
        HWBAR();
    }

    int bufR = 0, bufS = 2;
    for (int kt = 0; kt < NKT8; ++kt) {
        const short* bp = &lds[bufR * BUF_SHORTS];

        // issue stage of tile kt+2 (into bufS: nobody reads it for 2 iters)
        f32x4 fr[8];
        if (kt < NKT8 - 2) {
            if constexpr (ASRC == 1) {
                STAGE_A1(kt + 2, bufS);
                STAGE_B(kt + 2, bufS);
            } else {
                LOAD_A0(kt + 2, fr);
                STAGE_B(kt + 2, bufS);
            }
            SCHEDB();  // pin issue point
        }

        // compute: 2 half-K phases, 16 MFMA each
#pragma unroll
        for (int kk = 0; kk < 2; ++kk) {
            s16x8 af[4], bfr[4];
#pragma unroll
            for (int mi = 0; mi < 4; ++mi)
                af[mi] = *(const s16x8*)&bp[(wm * 64 + mi * 16 + lr) * 64 +
                                            (((kk * 4 + lg) ^ (lr & 7)) * 8)];
#pragma unroll
            for (int ni = 0; ni < 4; ++ni)
                bfr[ni] = *(const s16x8*)&bp[16384 + (wn * 64 + ni * 16 + lr) * 64 +
                                             (((kk * 4 + lg) ^ (lr & 7)) * 8)];
            __builtin_amdgcn_s_setprio(1);
#pragma unroll
            for (int mi = 0; mi < 4; ++mi)
#pragma unroll
                for (int ni = 0; ni < 4; ++ni)
                    acc[mi][ni] = __builtin_amdgcn_mfma_f32_16x16x32_bf16(
                        af[mi], bfr[ni], acc[mi][ni], 0, 0, 0);
            __builtin_amdgcn_s_setprio(0);
        }

        // end-of-iter sync: tile kt+1 must be landed for all waves
        if constexpr (ASRC == 0) {
            if (kt < NKT8 - 2) {
                VMCNT(2);  // A-regs(kt+2) + B(kt+1) landed; B(kt+2) may fly
                SCHEDB();
                WRITE_A0(bufS, fr);
                LGKM0();   // drain ds_writes (and frag reads)
                SCHEDB();
                HWBAR();
            } else if (kt == NKT8 - 2) {
                VMCNT(0);  // drain B(7)
                SCHEDB();
                HWBAR();
            }  // kt == 7: no sync needed
        } else {
            if (kt < NKT8 - 2) {
                VMCNT(6);  // kt+1's 6 landed; kt+2's 6 in flight
                SCHEDB();
                HWBAR();
            } else if (kt == NKT8 - 2) {
                VMCNT(0);
                SCHEDB();
                HWBAR();
            }
        }
        bufR = (bufR == 2) ? 0 : bufR + 1;
        bufS = (bufS == 2) ? 0 : bufS + 1;
    }
#undef STAGE_B
#undef STAGE_A1
#undef LOAD_A0
#undef WRITE_A0

    // C/D layout: col = lane&15, row = (lane>>4)*4 + reg
    const int rb = brow + wm * 64 + lg * 4;
    const int cb = bcol + wn * 64 + lr;

    if constexpr (EPI == 2) {
#pragma unroll
        for (int mi = 0; mi < 4; ++mi) {
#pragma unroll
            for (int r = 0; r < 4; ++r) {
                int row = rb + mi * 16 + r;
                if (row < N_NODES_C) {
#pragma unroll
                    for (int ni = 0; ni < 4; ++ni)
                        Cout[(size_t)row * DC + cb + ni * 16] = f2bf(acc[mi][ni][r]);
                }
            }
        }
    } else {
        float bv[4], wv[4];
#pragma unroll
        for (int ni = 0; ni < 4; ++ni) {
            bv[ni] = bias[cb + ni * 16];
            wv[ni] = w2a[cb + ni * 16];
        }
#pragma unroll
        for (int mi = 0; mi < 4; ++mi) {
#pragma unroll
            for (int r = 0; r < 4; ++r) {
                float sum = 0.f;
#pragma unroll
                for (int ni = 0; ni < 4; ++ni) {
                    float v = fmaxf(acc[mi][ni][r] + bv[ni], 0.0f);
                    sum += v * wv[ni];
                }
#pragma unroll
                for (int off = 1; off < 16; off <<= 1) sum += __shfl_xor(sum, off, 64);
                int row = rb + mi * 16 + r;
                if (lr == 0 && row < N_NODES_C) atomicAdd(&s_out[row], sum);
            }
        }
    }
}

// ---------------- launch ----------------

extern "C" void kernel_launch(void* const* d_in, const int* in_sizes, int n_in,
                              void* d_out, int out_size, void* d_ws, size_t ws_size,
                              hipStream_t stream) {
    const float* x     = (const float*)d_in[0];
    const int*   ei    = (const int*)d_in[1];
    const int*   batch = (const int*)d_in[2];
    const float* W1a   = (const float*)d_in[3];
    const float* b1a   = (const float*)d_in[4];
    const float* W1b   = (const float*)d_in[5];
    const float* b1b   = (const float*)d_in[6];
    const float* W2a   = (const float*)d_in[7];
    const float* b2a   = (const float*)d_in[8];
    const float* W2b   = (const float*)d_in[9];
    const float* b2b   = (const float*)d_in[10];
    float* out = (float*)d_out;

    char* w = (char*)d_ws;
    short* z1   = (short*)(w);                  // 102,400,000
    short* y    = (short*)(w + 102400000);      // 102,400,000
    short* WT1  = (short*)(w + 204800000);      // 524,288
    short* WT2  = (short*)(w + 205324288);      // 524,288
    float* sbuf = (float*)(w + 205848576);      // 400,000
    float* aggs = (float*)(w + 206248576);      // 400,000
    int*   cnt  = (int*)  (w + 206648576);      // 400,000
    int*   offb = (int*)  (w + 207048576);      // 400,000
    int*   ssrc = (int*)  (w + 207448576);      // 600,000
    int*   bsum = (int*)  (w + 208048576);      // 512
    float* gsum = (float*)(w + 208049088);      // 256
    float* gcnt = (float*)(w + 208049344);      // 256

    // allow 144 KB dynamic LDS (gfx950 has 160 KB/CU)
    hipFuncSetAttribute(reinterpret_cast<const void*>(&gemm8_k<0, 2>),
                        hipFuncAttributeMaxDynamicSharedMemorySize, LDS_BYTES);
    hipFuncSetAttribute(reinterpret_cast<const void*>(&gemm8_k<1, 1>),
                        hipFuncAttributeMaxDynamicSharedMemorySize, LDS_BYTES);

    zero_k<<<391, 256, 0, stream>>>(sbuf, aggs, cnt, gsum, gcnt);
    transpose_w<<<dim3(16, 16), 256, 0, stream>>>(W1a, WT1);
    transpose_w<<<dim3(16, 16), 256, 0, stream>>>(W1b, WT2);

    // CSR build (independent of GEMM0)
    hist_k<<<586, 256, 0, stream>>>(ei, cnt);
    scan1_k<<<NSCAN_BLK, 1024, 0, stream>>>(cnt, offb, bsum);
    scan2_k<<<1, 128, 0, stream>>>(bsum);
    scan3_k<<<NSCAN_BLK, 1024, 0, stream>>>(offb, bsum);
    place_k<<<586, 256, 0, stream>>>(ei, offb, ssrc);

    // y = bf16(x) @ W1a  (f32 A, fused convert in staging)
    gemm8_k<0, 2><<<NWG8, 512, LDS_BYTES, stream>>>(x, WT1, nullptr, y, nullptr, nullptr);
    // z1 = relu(y + agg(y) + b1a)
    gather_relu_k<<<25000, 256, 0, stream>>>(y, offb, ssrc, b1a, z1);
    // s = relu(z1 @ W1b + b1b) . W2a
    gemm8_k<1, 1><<<NWG8, 512, LDS_BYTES, stream>>>(z1, WT2, b1b, nullptr, W2a, sbuf);

    edge_scalar<<<586, 256, 0, stream>>>(ei, sbuf, aggs);
    node_pool<<<391, 256, 0, stream>>>(sbuf, aggs, batch, b2a, gsum, gcnt);
    finalize_k<<<1, 64, 0, stream>>>(gsum, gcnt, W2b, b2b, out);
}